// Round 12
// baseline (1422.840 us; speedup 1.0000x reference)
//
#include <hip/hip_runtime.h>
#include <hip/hip_bf16.h>
#include <stdint.h>

#define NN 8192
#define FD 690
#define NH 3
#define KPAD 704   // F_IN padded to mult of 64
#define OPAD 768   // F_OUT padded to mult of 128 (row FD holds constant 1 -> Z column)
#define USTRIDE 704
#define KS 4       // K-split for k_pv (2304 blocks = 4.5 rounds @ 2/CU)
#define LOG2E 1.4426950408889634f

typedef __attribute__((ext_vector_type(8))) short bf16x8;
typedef __attribute__((ext_vector_type(4))) float f32x4;

typedef __attribute__((address_space(1))) const void gas_t;
typedef __attribute__((address_space(3))) void las_t;

__device__ __forceinline__ void async_ld16(const void* g, void* l) {
  __builtin_amdgcn_global_load_lds((gas_t*)g, (las_t*)l, 16, 0, 0);
}

__device__ __forceinline__ float bf2f(unsigned short u) {
  return __uint_as_float(((unsigned int)u) << 16);
}
__device__ __forceinline__ unsigned short f2bf(float f) {
  __hip_bfloat16 h = __float2bfloat16(f);
  return *reinterpret_cast<unsigned short*>(&h);
}

// ---------- cast / pad ----------
__global__ __launch_bounds__(256) void k_cast_x(const float* __restrict__ x,
                                                unsigned short* __restrict__ xb) {
  int idx = blockIdx.x * 256 + threadIdx.x;
  if (idx >= NN * KPAD) return;
  int n = idx / KPAD, f = idx - n * KPAD;
  float v = (f < FD) ? x[(size_t)n * FD + f] : 0.f;
  xb[idx] = f2bf(v);
}

__global__ __launch_bounds__(256) void k_cast_wt(const float* __restrict__ W,
                                                 unsigned short* __restrict__ wt) {
  int idx = blockIdx.x * 256 + threadIdx.x;
  if (idx >= NH * OPAD * KPAD) return;
  int h = idx / (OPAD * KPAD);
  int rem = idx - h * OPAD * KPAD;
  int o = rem / KPAD, f = rem - o * KPAD;
  float v = (o < FD && f < FD) ? W[((size_t)h * FD + f) * FD + o] : 0.f;
  wt[idx] = f2bf(v);
}

// ---------- adjacency -> bitmask ----------
__global__ __launch_bounds__(256) void k_pack(const int* __restrict__ adj,
                                              uint64_t* __restrict__ bm) {
  int wid = (blockIdx.x * 256 + threadIdx.x) >> 6;
  int lane = threadIdx.x & 63;
  int i = wid >> 7, wj = wid & 127;
  int v = adj[(int64_t)i * NN + wj * 64 + lane];
  uint64_t m = __ballot(v > 0);
  if (lane == 0) bm[i * 128 + wj] = m;
}

// ---------- WhT[h][o][n] = sum_f x[n][f] W[h][f][o]  (bf16 out; row FD = 1.0) ----------
// Epilogue additionally folds the a1/a2 score projections (f32, atomics).
__global__ __launch_bounds__(512) void k_gemm_wht(const unsigned short* __restrict__ wt,
                                                  const unsigned short* __restrict__ xb,
                                                  const float* __restrict__ a,
                                                  unsigned short* __restrict__ wht,
                                                  float* __restrict__ a1acc,
                                                  float* __restrict__ a2acc) {
  const int m0 = blockIdx.x * 128;   // o
  const int n0 = blockIdx.y * 256;   // node
  const int h  = blockIdx.z;
  const int tid = threadIdx.x;
  const int w = tid >> 6, l = tid & 63;
  const int wm = w >> 2, wn = w & 3;
  __shared__ unsigned short As[128 * 64];
  __shared__ unsigned short Bs[256 * 64];
  const unsigned short* Ag = wt + (size_t)h * OPAD * KPAD;
  f32x4 acc[4][4] = {};
  for (int kt = 0; kt < KPAD / 64; ++kt) {
    const int k0 = kt * 64;
#pragma unroll
    for (int r = 0; r < 2; ++r) {
      const unsigned short* g = Ag + (size_t)(m0 + r * 64 + w * 8 + (l >> 3)) * KPAD + k0 + (l & 7) * 8;
      async_ld16(g, &As[(r * 64 + w * 8) * 64]);
    }
#pragma unroll
    for (int r = 0; r < 4; ++r) {
      const unsigned short* g = xb + (size_t)(n0 + r * 64 + w * 8 + (l >> 3)) * KPAD + k0 + (l & 7) * 8;
      async_ld16(g, &Bs[(r * 64 + w * 8) * 64]);
    }
    __syncthreads();
#pragma unroll
    for (int ks = 0; ks < 2; ++ks) {
      bf16x8 af[4], bfr[4];
#pragma unroll
      for (int mi = 0; mi < 4; ++mi)
        af[mi] = *reinterpret_cast<const bf16x8*>(
            &As[(wm * 64 + mi * 16 + (l & 15)) * 64 + ks * 32 + (l >> 4) * 8]);
#pragma unroll
      for (int ni = 0; ni < 4; ++ni)
        bfr[ni] = *reinterpret_cast<const bf16x8*>(
            &Bs[(wn * 64 + ni * 16 + (l & 15)) * 64 + ks * 32 + (l >> 4) * 8]);
#pragma unroll
      for (int mi = 0; mi < 4; ++mi)
#pragma unroll
        for (int ni = 0; ni < 4; ++ni)
          acc[mi][ni] = __builtin_amdgcn_mfma_f32_16x16x32_bf16(af[mi], bfr[ni], acc[mi][ni], 0, 0, 0);
    }
    __syncthreads();
  }
  unsigned short* Wh = wht + (size_t)h * OPAD * NN;
#pragma unroll
  for (int mi = 0; mi < 4; ++mi)
#pragma unroll
    for (int j = 0; j < 4; ++j) {
      int o = m0 + wm * 64 + mi * 16 + (l >> 4) * 4 + j;
#pragma unroll
      for (int ni = 0; ni < 4; ++ni) {
        int n = n0 + wn * 64 + ni * 16 + (l & 15);
        float val = (o == FD) ? 1.0f : acc[mi][ni][j];  // pad rows are exactly 0; row FD = ones
        Wh[(size_t)o * NN + n] = f2bf(val);
      }
    }
  // ---- a1/a2 partial projections (f32 acc, per-(n) atomics) ----
  const float* ap1 = a + h * 2 * FD;
  const float* ap2 = ap1 + FD;
  float av1[4][4], av2[4][4];
#pragma unroll
  for (int mi = 0; mi < 4; ++mi)
#pragma unroll
    for (int j = 0; j < 4; ++j) {
      int o = m0 + wm * 64 + mi * 16 + (l >> 4) * 4 + j;
      bool ok = (o < FD);
      av1[mi][j] = ok ? ap1[o] : 0.f;
      av2[mi][j] = ok ? ap2[o] : 0.f;
    }
#pragma unroll
  for (int ni = 0; ni < 4; ++ni) {
    float p1 = 0.f, p2 = 0.f;
#pragma unroll
    for (int mi = 0; mi < 4; ++mi)
#pragma unroll
      for (int j = 0; j < 4; ++j) {
        p1 += acc[mi][ni][j] * av1[mi][j];
        p2 += acc[mi][ni][j] * av2[mi][j];
      }
    int n = n0 + wn * 64 + ni * 16 + (l & 15);
    unsafeAtomicAdd(&a1acc[h * NN + n], p1);
    unsafeAtomicAdd(&a2acc[h * NN + n], p2);
  }
}

// ---------- E/F factors from accumulated a1/a2 ----------
__global__ __launch_bounds__(256) void k_exp(const float* __restrict__ a1acc,
                                             const float* __restrict__ a2acc,
                                             float* __restrict__ e1s, float* __restrict__ f1s,
                                             float* __restrict__ e2s, float* __restrict__ f2s) {
  int i = blockIdx.x * 256 + threadIdx.x;
  if (i >= NH * NN) return;
  float s1 = a1acc[i] * LOG2E, s2 = a2acc[i] * LOG2E;
  e1s[i] = exp2f(s1);
  f1s[i] = exp2f(0.2f * s1);
  e2s[i] = exp2f(s2);
  f2s[i] = exp2f(0.2f * s2);
}

// ---------- PV: U[h][i][n] += sum_{j in kseg} w_ij WhT[n][j] ; column FD gives Z_i ----------
// w_ij = max(E1_i*E2_j, F1_i*F2_j)  (== exp2(log2e*lrelu(a1_i+a2_j)), exp2 monotone)
// BM=256 x BN=128 (r11 analysis: B LLC traffic  ~ 1/BM; 4.8GB -> 1.2GB), 8 waves 4x2,
// wave tile 64x64 (acc 64 regs). r7's proven 2-barrier skeleton. genA writes 4
// consecutive k per lane -> ds_write_b64; per-lane masks; E1/F1 preloaded per wave.
__global__ __launch_bounds__(512, 2) void k_pv(const unsigned short* __restrict__ wht,
                                               const float* __restrict__ e1s,
                                               const float* __restrict__ f1s,
                                               const float* __restrict__ e2s,
                                               const float* __restrict__ f2s,
                                               const uint64_t* __restrict__ bm,
                                               float* __restrict__ U) {
  const int m0 = blockIdx.x * 256;          // node rows i
  const int n0 = blockIdx.y * 128;          // feature cols
  const int h    = blockIdx.z / KS;
  const int kseg = blockIdx.z % KS;
  const int tid = threadIdx.x;
  const int w = tid >> 6, l = tid & 63;
  const int wm = w >> 1, wn = w & 1;
  __shared__ unsigned short As[256 * 64];   // 32KB, XOR-swizzled 16B blocks
  __shared__ unsigned short Bs[128 * 64];   // 16KB, XOR-swizzled
  const unsigned short* Bg = wht + (size_t)h * OPAD * NN;

  // wave's 32 A-rows are fixed: preload E1/F1 (lane covers row w*32 + s*4 + (l>>4))
  float E1p[8], F1p[8];
#pragma unroll
  for (int s = 0; s < 8; ++s) {
    int row = m0 + w * 32 + s * 4 + (l >> 4);
    E1p[s] = e1s[h * NN + row];
    F1p[s] = f1s[h * NN + row];
  }

  const int kt0 = kseg * (128 / KS);
  const int ktend = kt0 + 128 / KS;

  f32x4 acc[4][4] = {};

  for (int kt = kt0; kt < ktend; ++kt) {
    const int k0 = kt * 64;
    // per-lane inputs for genA FIRST (so genA waits only on these, not staging)
    const f32x4 e2v = *reinterpret_cast<const f32x4*>(&e2s[h * NN + k0 + (l & 15) * 4]);
    const f32x4 f2v = *reinterpret_cast<const f32x4*>(&f2s[h * NN + k0 + (l & 15) * 4]);
    uint2 mr[8];
#pragma unroll
    for (int s = 0; s < 8; ++s)
      mr[s] = *reinterpret_cast<const uint2*>(
          &bm[(size_t)(m0 + w * 32 + s * 4 + (l >> 4)) * 128 + kt]);
    // stage B tile (128 x 64) via gload_lds: linear dest, source k-block pre-swizzled
#pragma unroll
    for (int call = 0; call < 2; ++call) {
      int c = call * 512 + tid;             // 16B-chunk index in [0,1024)
      int row = c >> 3;
      int kb  = c & 7;
      int kbs = kb ^ (row & 7);
      const unsigned short* g = Bg + (size_t)(n0 + row) * NN + k0 + kbs * 8;
      async_ld16(g, &Bs[(size_t)c * 8]);
    }
    // genA: lane handles 4 consecutive k of one row; 4 rows per step, 8 steps = 32 rows/wave
#pragma unroll
    for (int s = 0; s < 8; ++s) {
      int row = w * 32 + s * 4 + (l >> 4);
      uint32_t half = ((l & 15) < 8) ? mr[s].x : mr[s].y;
      uint32_t m4 = (half >> (((l & 15) & 7) * 4)) & 0xF;
      uint32_t lo, hi;
      {
        float e0 = fmaxf(E1p[s] * e2v[0], F1p[s] * f2v[0]);
        float e1 = fmaxf(E1p[s] * e2v[1], F1p[s] * f2v[1]);
        e0 = (m4 & 1u) ? e0 : 0.f;
        e1 = (m4 & 2u) ? e1 : 0.f;
        lo = (uint32_t)f2bf(e0) | ((uint32_t)f2bf(e1) << 16);
      }
      {
        float e2_ = fmaxf(E1p[s] * e2v[2], F1p[s] * f2v[2]);
        float e3 = fmaxf(E1p[s] * e2v[3], F1p[s] * f2v[3]);
        e2_ = (m4 & 4u) ? e2_ : 0.f;
        e3 = (m4 & 8u) ? e3 : 0.f;
        hi = (uint32_t)f2bf(e2_) | ((uint32_t)f2bf(e3) << 16);
      }
      int kb = (l & 15) >> 1;
      int phys = kb ^ (row & 7);
      int addr = row * 64 + phys * 8 + ((l & 15) & 1) * 4;   // elems; 8B aligned
      uint2 val; val.x = lo; val.y = hi;
      *reinterpret_cast<uint2*>(&As[addr]) = val;
    }
    __syncthreads();   // drains gload_lds vmcnt + A ds_writes

#pragma unroll
    for (int ks = 0; ks < 2; ++ks) {
      bf16x8 bfr[4];
#pragma unroll
      for (int ni = 0; ni < 4; ++ni) {
        int row = wn * 64 + ni * 16 + (l & 15);
        int phys = (ks * 4 + (l >> 4)) ^ (row & 7);
        bfr[ni] = *reinterpret_cast<const bf16x8*>(&Bs[row * 64 + phys * 8]);
      }
#pragma unroll
      for (int mi = 0; mi < 4; ++mi) {
        int arow = wm * 64 + mi * 16 + (l & 15);
        int aphys = (ks * 4 + (l >> 4)) ^ (arow & 7);
        bf16x8 af = *reinterpret_cast<const bf16x8*>(&As[arow * 64 + aphys * 8]);
#pragma unroll
        for (int ni = 0; ni < 4; ++ni)
          acc[mi][ni] = __builtin_amdgcn_mfma_f32_16x16x32_bf16(af, bfr[ni], acc[mi][ni], 0, 0, 0);
      }
    }
    __syncthreads();
  }

#pragma unroll
  for (int mi = 0; mi < 4; ++mi)
#pragma unroll
    for (int j = 0; j < 4; ++j) {
      int i = m0 + wm * 64 + mi * 16 + (l >> 4) * 4 + j;
#pragma unroll
      for (int ni = 0; ni < 4; ++ni) {
        int n = n0 + wn * 64 + ni * 16 + (l & 15);
        if (n <= FD) unsafeAtomicAdd(&U[((size_t)h * NN + i) * USTRIDE + n], acc[mi][ni][j]);
      }
    }
}

// ---------- y = elu(mean_h U[h][i][o] / U[h][i][FD]) ----------
__global__ __launch_bounds__(256) void k_final(const float* __restrict__ U,
                                               float* __restrict__ y) {
  int idx = blockIdx.x * 256 + threadIdx.x;
  if (idx >= NN * FD) return;
  int i = idx / FD, o = idx - i * FD;
  const size_t HS = (size_t)NN * USTRIDE;
  float s = 0.f;
#pragma unroll
  for (int h = 0; h < NH; ++h) {
    size_t b = h * HS + (size_t)i * USTRIDE;
    s += U[b + o] / U[b + FD];
  }
  s *= (1.f / 3.f);
  y[idx] = s > 0.f ? s : (expf(s) - 1.f);
}

extern "C" void kernel_launch(void* const* d_in, const int* in_sizes, int n_in,
                              void* d_out, int out_size, void* d_ws, size_t ws_size,
                              hipStream_t stream) {
  const float* x   = (const float*)d_in[0];
  const int*   adj = (const int*)d_in[1];
  const float* W   = (const float*)d_in[2];
  const float* a   = (const float*)d_in[3];
  float* y = (float*)d_out;

  char* ws = (char*)d_ws;
  size_t off = 0;
  auto alloc = [&](size_t bytes) {
    void* p = ws + off;
    off = (off + bytes + 255) & ~(size_t)255;
    return p;
  };
  unsigned short* xb  = (unsigned short*)alloc((size_t)NN * KPAD * 2);
  unsigned short* wt  = (unsigned short*)alloc((size_t)NH * OPAD * KPAD * 2);
  unsigned short* wht = (unsigned short*)alloc((size_t)NH * OPAD * NN * 2);
  float* e1s = (float*)alloc((size_t)NH * NN * 4);
  float* f1s = (float*)alloc((size_t)NH * NN * 4);
  float* e2s = (float*)alloc((size_t)NH * NN * 4);
  float* f2s = (float*)alloc((size_t)NH * NN * 4);
  uint64_t* bm = (uint64_t*)alloc((size_t)NN * 128 * 8);
  float* U = (float*)alloc((size_t)NH * NN * USTRIDE * 4);
  float* a1acc = (float*)alloc((size_t)NH * NN * 4);
  float* a2acc = (float*)alloc((size_t)NH * NN * 4);
  (void)ws_size; (void)in_sizes; (void)n_in; (void)out_size;

  hipMemsetAsync(U, 0, (size_t)NH * NN * USTRIDE * 4, stream);
  hipMemsetAsync(a1acc, 0, (size_t)NH * NN * 4 * 2, stream);

  k_cast_x<<<(NN * KPAD + 255) / 256, 256, 0, stream>>>(x, xb);
  k_cast_wt<<<(NH * OPAD * KPAD + 255) / 256, 256, 0, stream>>>(W, wt);
  k_pack<<<NN * 128 / 4, 256, 0, stream>>>(adj, bm);
  k_gemm_wht<<<dim3(OPAD / 128, NN / 256, NH), 512, 0, stream>>>(wt, xb, a, wht, a1acc, a2acc);
  k_exp<<<(NH * NN + 255) / 256, 256, 0, stream>>>(a1acc, a2acc, e1s, f1s, e2s, f2s);
  k_pv<<<dim3(NN / 256, OPAD / 128, NH * KS), 512, 0, stream>>>(wht, e1s, f1s, e2s, f2s, bm, U);
  k_final<<<(NN * FD + 255) / 256, 256, 0, stream>>>(U, y);
}

// Round 13
// 684.663 us; speedup vs baseline: 2.0782x; 2.0782x over previous
//
#include <hip/hip_runtime.h>
#include <hip/hip_bf16.h>
#include <stdint.h>

#define NN 8192
#define FD 690
#define NH 3
#define KPAD 704   // F_IN padded to mult of 64
#define OPAD 768   // F_OUT padded to mult of 128 (row FD holds constant 1 -> Z column)
#define USTRIDE 704
#define KS 2       // K-split for k_pv: grid 2304 = exactly 9 blocks/CU
#define LOG2E 1.4426950408889634f

typedef __attribute__((ext_vector_type(8))) short bf16x8;
typedef __attribute__((ext_vector_type(4))) float f32x4;

typedef __attribute__((address_space(1))) const void gas_t;
typedef __attribute__((address_space(3))) void las_t;

__device__ __forceinline__ void async_ld16(const void* g, void* l) {
  __builtin_amdgcn_global_load_lds((gas_t*)g, (las_t*)l, 16, 0, 0);
}

__device__ __forceinline__ float bf2f(unsigned short u) {
  return __uint_as_float(((unsigned int)u) << 16);
}
__device__ __forceinline__ unsigned short f2bf(float f) {
  __hip_bfloat16 h = __float2bfloat16(f);
  return *reinterpret_cast<unsigned short*>(&h);
}
__device__ __forceinline__ float uniformf(float x) {
  return __uint_as_float(__builtin_amdgcn_readfirstlane(__float_as_uint(x)));
}
// r = bit[lane] of (hi:lo) ? e : 0 — mask forced scalar via readfirstlane upstream
__device__ __forceinline__ float selbit(float e, uint32_t lo, uint32_t hi) {
  uint64_t m = ((uint64_t)hi << 32) | lo;
  float r;
  asm("v_cndmask_b32 %0, 0, %1, %2" : "=v"(r) : "v"(e), "s"(m));
  return r;
}

// ---------- cast / pad ----------
__global__ __launch_bounds__(256) void k_cast_x(const float* __restrict__ x,
                                                unsigned short* __restrict__ xb) {
  int idx = blockIdx.x * 256 + threadIdx.x;
  if (idx >= NN * KPAD) return;
  int n = idx / KPAD, f = idx - n * KPAD;
  float v = (f < FD) ? x[(size_t)n * FD + f] : 0.f;
  xb[idx] = f2bf(v);
}

__global__ __launch_bounds__(256) void k_cast_wt(const float* __restrict__ W,
                                                 unsigned short* __restrict__ wt) {
  int idx = blockIdx.x * 256 + threadIdx.x;
  if (idx >= NH * OPAD * KPAD) return;
  int h = idx / (OPAD * KPAD);
  int rem = idx - h * OPAD * KPAD;
  int o = rem / KPAD, f = rem - o * KPAD;
  float v = (o < FD && f < FD) ? W[((size_t)h * FD + f) * FD + o] : 0.f;
  wt[idx] = f2bf(v);
}

// ---------- adjacency -> bitmask ----------
__global__ __launch_bounds__(256) void k_pack(const int* __restrict__ adj,
                                              uint64_t* __restrict__ bm) {
  int wid = (blockIdx.x * 256 + threadIdx.x) >> 6;
  int lane = threadIdx.x & 63;
  int i = wid >> 7, wj = wid & 127;
  int v = adj[(int64_t)i * NN + wj * 64 + lane];
  uint64_t m = __ballot(v > 0);
  if (lane == 0) bm[i * 128 + wj] = m;
}

// ---------- WhT[h][o][n] = sum_f x[n][f] W[h][f][o]  (bf16 out; row FD = 1.0) ----------
// Epilogue additionally folds the a1/a2 score projections (f32, atomics).
__global__ __launch_bounds__(512) void k_gemm_wht(const unsigned short* __restrict__ wt,
                                                  const unsigned short* __restrict__ xb,
                                                  const float* __restrict__ a,
                                                  unsigned short* __restrict__ wht,
                                                  float* __restrict__ a1acc,
                                                  float* __restrict__ a2acc) {
  const int m0 = blockIdx.x * 128;   // o
  const int n0 = blockIdx.y * 256;   // node
  const int h  = blockIdx.z;
  const int tid = threadIdx.x;
  const int w = tid >> 6, l = tid & 63;
  const int wm = w >> 2, wn = w & 3;
  __shared__ unsigned short As[128 * 64];
  __shared__ unsigned short Bs[256 * 64];
  const unsigned short* Ag = wt + (size_t)h * OPAD * KPAD;
  f32x4 acc[4][4] = {};
  for (int kt = 0; kt < KPAD / 64; ++kt) {
    const int k0 = kt * 64;
#pragma unroll
    for (int r = 0; r < 2; ++r) {
      const unsigned short* g = Ag + (size_t)(m0 + r * 64 + w * 8 + (l >> 3)) * KPAD + k0 + (l & 7) * 8;
      async_ld16(g, &As[(r * 64 + w * 8) * 64]);
    }
#pragma unroll
    for (int r = 0; r < 4; ++r) {
      const unsigned short* g = xb + (size_t)(n0 + r * 64 + w * 8 + (l >> 3)) * KPAD + k0 + (l & 7) * 8;
      async_ld16(g, &Bs[(r * 64 + w * 8) * 64]);
    }
    __syncthreads();
#pragma unroll
    for (int ks = 0; ks < 2; ++ks) {
      bf16x8 af[4], bfr[4];
#pragma unroll
      for (int mi = 0; mi < 4; ++mi)
        af[mi] = *reinterpret_cast<const bf16x8*>(
            &As[(wm * 64 + mi * 16 + (l & 15)) * 64 + ks * 32 + (l >> 4) * 8]);
#pragma unroll
      for (int ni = 0; ni < 4; ++ni)
        bfr[ni] = *reinterpret_cast<const bf16x8*>(
            &Bs[(wn * 64 + ni * 16 + (l & 15)) * 64 + ks * 32 + (l >> 4) * 8]);
#pragma unroll
      for (int mi = 0; mi < 4; ++mi)
#pragma unroll
        for (int ni = 0; ni < 4; ++ni)
          acc[mi][ni] = __builtin_amdgcn_mfma_f32_16x16x32_bf16(af[mi], bfr[ni], acc[mi][ni], 0, 0, 0);
    }
    __syncthreads();
  }
  unsigned short* Wh = wht + (size_t)h * OPAD * NN;
#pragma unroll
  for (int mi = 0; mi < 4; ++mi)
#pragma unroll
    for (int j = 0; j < 4; ++j) {
      int o = m0 + wm * 64 + mi * 16 + (l >> 4) * 4 + j;
#pragma unroll
      for (int ni = 0; ni < 4; ++ni) {
        int n = n0 + wn * 64 + ni * 16 + (l & 15);
        float val = (o == FD) ? 1.0f : acc[mi][ni][j];  // pad rows are exactly 0; row FD = ones
        Wh[(size_t)o * NN + n] = f2bf(val);
      }
    }
  // ---- a1/a2 partial projections (f32 acc, per-(n) atomics) ----
  const float* ap1 = a + h * 2 * FD;
  const float* ap2 = ap1 + FD;
  float av1[4][4], av2[4][4];
#pragma unroll
  for (int mi = 0; mi < 4; ++mi)
#pragma unroll
    for (int j = 0; j < 4; ++j) {
      int o = m0 + wm * 64 + mi * 16 + (l >> 4) * 4 + j;
      bool ok = (o < FD);
      av1[mi][j] = ok ? ap1[o] : 0.f;
      av2[mi][j] = ok ? ap2[o] : 0.f;
    }
#pragma unroll
  for (int ni = 0; ni < 4; ++ni) {
    float p1 = 0.f, p2 = 0.f;
#pragma unroll
    for (int mi = 0; mi < 4; ++mi)
#pragma unroll
      for (int j = 0; j < 4; ++j) {
        p1 += acc[mi][ni][j] * av1[mi][j];
        p2 += acc[mi][ni][j] * av2[mi][j];
      }
    int n = n0 + wn * 64 + ni * 16 + (l & 15);
    unsafeAtomicAdd(&a1acc[h * NN + n], p1);
    unsafeAtomicAdd(&a2acc[h * NN + n], p2);
  }
}

// ---------- E/F factors from accumulated a1/a2 ----------
__global__ __launch_bounds__(256) void k_exp(const float* __restrict__ a1acc,
                                             const float* __restrict__ a2acc,
                                             float* __restrict__ e1s, float* __restrict__ f1s,
                                             float* __restrict__ e2s, float* __restrict__ f2s) {
  int i = blockIdx.x * 256 + threadIdx.x;
  if (i >= NH * NN) return;
  float s1 = a1acc[i] * LOG2E, s2 = a2acc[i] * LOG2E;
  e1s[i] = exp2f(s1);
  f1s[i] = exp2f(0.2f * s1);
  e2s[i] = exp2f(s2);
  f2s[i] = exp2f(0.2f * s2);
}

// ---------- PV: U[h][i][n] += sum_{j in kseg} w_ij WhT[n][j] ; column FD gives Z_i ----------
// w_ij = max(E1_i*E2_j, F1_i*F2_j)  (== exp2(log2e*lrelu(a1_i+a2_j)), exp2 monotone)
// r12 analysis: r7 is chain-bound with only 2 barrier groups/CU. Same tile math,
// finer granularity: 256-thread blocks (4 waves), BM=64 BN=256 (3 panels),
// LDS 40KB -> 4 blocks/CU = 4 independent barrier groups. E1/F1 in SGPRs
// (readfirstlane) to hold unified regs ~104 <= 128 (16 waves/CU).
__global__ __launch_bounds__(256, 4) void k_pv(const unsigned short* __restrict__ wht,
                                               const float* __restrict__ e1s,
                                               const float* __restrict__ f1s,
                                               const float* __restrict__ e2s,
                                               const float* __restrict__ f2s,
                                               const uint64_t* __restrict__ bm,
                                               float* __restrict__ U) {
  const int m0 = blockIdx.x * 64;           // node rows i
  const int n0 = blockIdx.y * 256;          // feature cols
  const int h    = blockIdx.z / KS;
  const int kseg = blockIdx.z % KS;
  const int tid = threadIdx.x;
  const int w = tid >> 6, l = tid & 63;
  const int wu = __builtin_amdgcn_readfirstlane(w);
  // XOR-swizzled [rows][64] tiles (16B-block index ^= row&7)
  __shared__ unsigned short As[64 * 64];    // 8KB
  __shared__ unsigned short Bs[256 * 64];   // 32KB
  const unsigned short* Bg = wht + (size_t)h * OPAD * NN;
  const uint64_t* bmw = bm + (size_t)(m0 + wu * 16) * 128;
  float E1v[16], F1v[16];                   // wave-uniform -> SGPRs via readfirstlane
#pragma unroll
  for (int r = 0; r < 16; ++r) {
    E1v[r] = uniformf(e1s[h * NN + m0 + wu * 16 + r]);
    F1v[r] = uniformf(f1s[h * NN + m0 + wu * 16 + r]);
  }

  const int kt0 = kseg * (128 / KS);
  const int ktend = kt0 + 128 / KS;

  f32x4 acc[4][4] = {};

  for (int kt = kt0; kt < ktend; ++kt) {
    const int k0 = kt * 64;
    // e2/f2 FIRST: genA waits only on these, not the staging drain
    const float e2v = e2s[h * NN + k0 + l];
    const float f2v = f2s[h * NN + k0 + l];
    // stage B (256 x 64) via gload_lds: linear dest, source k-block pre-swizzled
#pragma unroll
    for (int call = 0; call < 8; ++call) {
      int c = call * 256 + tid;             // 16B-chunk index in [0,2048)
      int row = c >> 3;
      int kb  = c & 7;
      int kbs = kb ^ (row & 7);
      const unsigned short* g = Bg + (size_t)(n0 + row) * NN + k0 + kbs * 8;
      async_ld16(g, &Bs[(size_t)c * 8]);
    }
    // generate A tile: wave handles 16 rows, lane = k within tile
#pragma unroll
    for (int r = 0; r < 16; ++r) {
      uint64_t mrow = bmw[(size_t)r * 128 + kt];
      uint32_t mlo = __builtin_amdgcn_readfirstlane((uint32_t)mrow);
      uint32_t mhi = __builtin_amdgcn_readfirstlane((uint32_t)(mrow >> 32));
      float e = fmaxf(E1v[r] * e2v, F1v[r] * f2v);
      e = selbit(e, mlo, mhi);
      As[(wu * 16 + r) * 64 + (l ^ ((r & 7) << 3))] = f2bf(e);
    }
    __syncthreads();

#pragma unroll
    for (int ks = 0; ks < 2; ++ks) {
      bf16x8 af[4], bfr[4];
#pragma unroll
      for (int mi = 0; mi < 4; ++mi) {
        int row = mi * 16 + (l & 15);
        af[mi] = *reinterpret_cast<const bf16x8*>(
            &As[row * 64 + (((ks * 4 + (l >> 4)) ^ (row & 7)) * 8)]);
      }
#pragma unroll
      for (int ni = 0; ni < 4; ++ni) {
        int row = w * 64 + ni * 16 + (l & 15);
        bfr[ni] = *reinterpret_cast<const bf16x8*>(
            &Bs[row * 64 + (((ks * 4 + (l >> 4)) ^ (row & 7)) * 8)]);
      }
#pragma unroll
      for (int mi = 0; mi < 4; ++mi)
#pragma unroll
        for (int ni = 0; ni < 4; ++ni)
          acc[mi][ni] = __builtin_amdgcn_mfma_f32_16x16x32_bf16(af[mi], bfr[ni], acc[mi][ni], 0, 0, 0);
    }
    __syncthreads();
  }

#pragma unroll
  for (int mi = 0; mi < 4; ++mi)
#pragma unroll
    for (int j = 0; j < 4; ++j) {
      int i = m0 + mi * 16 + (l >> 4) * 4 + j;
#pragma unroll
      for (int ni = 0; ni < 4; ++ni) {
        int n = n0 + w * 64 + ni * 16 + (l & 15);
        if (n <= FD) unsafeAtomicAdd(&U[((size_t)h * NN + i) * USTRIDE + n], acc[mi][ni][j]);
      }
    }
}

// ---------- y = elu(mean_h U[h][i][o] / U[h][i][FD]) ----------
__global__ __launch_bounds__(256) void k_final(const float* __restrict__ U,
                                               float* __restrict__ y) {
  int idx = blockIdx.x * 256 + threadIdx.x;
  if (idx >= NN * FD) return;
  int i = idx / FD, o = idx - i * FD;
  const size_t HS = (size_t)NN * USTRIDE;
  float s = 0.f;
#pragma unroll
  for (int h = 0; h < NH; ++h) {
    size_t b = h * HS + (size_t)i * USTRIDE;
    s += U[b + o] / U[b + FD];
  }
  s *= (1.f / 3.f);
  y[idx] = s > 0.f ? s : (expf(s) - 1.f);
}

extern "C" void kernel_launch(void* const* d_in, const int* in_sizes, int n_in,
                              void* d_out, int out_size, void* d_ws, size_t ws_size,
                              hipStream_t stream) {
  const float* x   = (const float*)d_in[0];
  const int*   adj = (const int*)d_in[1];
  const float* W   = (const float*)d_in[2];
  const float* a   = (const float*)d_in[3];
  float* y = (float*)d_out;

  char* ws = (char*)d_ws;
  size_t off = 0;
  auto alloc = [&](size_t bytes) {
    void* p = ws + off;
    off = (off + bytes + 255) & ~(size_t)255;
    return p;
  };
  unsigned short* xb  = (unsigned short*)alloc((size_t)NN * KPAD * 2);
  unsigned short* wt  = (unsigned short*)alloc((size_t)NH * OPAD * KPAD * 2);
  unsigned short* wht = (unsigned short*)alloc((size_t)NH * OPAD * NN * 2);
  float* e1s = (float*)alloc((size_t)NH * NN * 4);
  float* f1s = (float*)alloc((size_t)NH * NN * 4);
  float* e2s = (float*)alloc((size_t)NH * NN * 4);
  float* f2s = (float*)alloc((size_t)NH * NN * 4);
  uint64_t* bm = (uint64_t*)alloc((size_t)NN * 128 * 8);
  float* U = (float*)alloc((size_t)NH * NN * USTRIDE * 4);
  float* a1acc = (float*)alloc((size_t)NH * NN * 4);
  float* a2acc = (float*)alloc((size_t)NH * NN * 4);
  (void)ws_size; (void)in_sizes; (void)n_in; (void)out_size;

  hipMemsetAsync(U, 0, (size_t)NH * NN * USTRIDE * 4, stream);
  hipMemsetAsync(a1acc, 0, (size_t)NH * NN * 4 * 2, stream);

  k_cast_x<<<(NN * KPAD + 255) / 256, 256, 0, stream>>>(x, xb);
  k_cast_wt<<<(NH * OPAD * KPAD + 255) / 256, 256, 0, stream>>>(W, wt);
  k_pack<<<NN * 128 / 4, 256, 0, stream>>>(adj, bm);
  k_gemm_wht<<<dim3(OPAD / 128, NN / 256, NH), 512, 0, stream>>>(wt, xb, a, wht, a1acc, a2acc);
  k_exp<<<(NH * NN + 255) / 256, 256, 0, stream>>>(a1acc, a2acc, e1s, f1s, e2s, f2s);
  k_pv<<<dim3(NN / 64, OPAD / 256, NH * KS), 256, 0, stream>>>(wht, e1s, f1s, e2s, f2s, bm, U);
  k_final<<<(NN * FD + 255) / 256, 256, 0, stream>>>(U, y);
}

// Round 14
// 635.679 us; speedup vs baseline: 2.2383x; 1.0771x over previous
//
#include <hip/hip_runtime.h>
#include <hip/hip_bf16.h>
#include <stdint.h>

#define NN 8192
#define FD 690
#define NH 3
#define KPAD 704   // F_IN padded to mult of 64
#define OPAD 768   // F_OUT padded to mult of 128 (row FD holds constant 1 -> Z column)
#define USTRIDE 704
#define KS 2       // K-split factor for k_pv
#define LOG2E 1.4426950408889634f

typedef __attribute__((ext_vector_type(8))) short bf16x8;
typedef __attribute__((ext_vector_type(4))) float f32x4;

typedef __attribute__((address_space(1))) const void gas_t;
typedef __attribute__((address_space(3))) void las_t;

__device__ __forceinline__ void async_ld16(const void* g, void* l) {
  __builtin_amdgcn_global_load_lds((gas_t*)g, (las_t*)l, 16, 0, 0);
}

__device__ __forceinline__ float bf2f(unsigned short u) {
  return __uint_as_float(((unsigned int)u) << 16);
}
__device__ __forceinline__ unsigned short f2bf(float f) {
  __hip_bfloat16 h = __float2bfloat16(f);
  return *reinterpret_cast<unsigned short*>(&h);
}
// r = bit[lane] of (hi:lo) ? e : 0 — mask forced scalar via readfirstlane upstream
__device__ __forceinline__ float selbit(float e, uint32_t lo, uint32_t hi) {
  uint64_t m = ((uint64_t)hi << 32) | lo;
  float r;
  asm("v_cndmask_b32 %0, 0, %1, %2" : "=v"(r) : "v"(e), "s"(m));
  return r;
}

// ---------- fused cast / pad (xb then wt by index range) ----------
__global__ __launch_bounds__(256) void k_cast(const float* __restrict__ x,
                                              const float* __restrict__ W,
                                              unsigned short* __restrict__ xb,
                                              unsigned short* __restrict__ wt) {
  int idx = blockIdx.x * 256 + threadIdx.x;
  if (idx < NN * KPAD) {
    int n = idx / KPAD, f = idx - n * KPAD;
    float v = (f < FD) ? x[(size_t)n * FD + f] : 0.f;
    xb[idx] = f2bf(v);
    return;
  }
  idx -= NN * KPAD;
  if (idx >= NH * OPAD * KPAD) return;
  int h = idx / (OPAD * KPAD);
  int rem = idx - h * OPAD * KPAD;
  int o = rem / KPAD, f = rem - o * KPAD;
  float v = (o < FD && f < FD) ? W[((size_t)h * FD + f) * FD + o] : 0.f;
  wt[idx] = f2bf(v);
}

// ---------- adjacency -> bitmask ----------
__global__ __launch_bounds__(256) void k_pack(const int* __restrict__ adj,
                                              uint64_t* __restrict__ bm) {
  int wid = (blockIdx.x * 256 + threadIdx.x) >> 6;
  int lane = threadIdx.x & 63;
  int i = wid >> 7, wj = wid & 127;
  int v = adj[(int64_t)i * NN + wj * 64 + lane];
  uint64_t m = __ballot(v > 0);
  if (lane == 0) bm[i * 128 + wj] = m;
}

// ---------- WhT[h][o][n] = sum_f x[n][f] W[h][f][o]  (bf16 out; row FD = 1.0) ----------
// Epilogue additionally folds the a1/a2 score projections (f32, atomics).
__global__ __launch_bounds__(512) void k_gemm_wht(const unsigned short* __restrict__ wt,
                                                  const unsigned short* __restrict__ xb,
                                                  const float* __restrict__ a,
                                                  unsigned short* __restrict__ wht,
                                                  float* __restrict__ a1acc,
                                                  float* __restrict__ a2acc) {
  const int m0 = blockIdx.x * 128;   // o
  const int n0 = blockIdx.y * 256;   // node
  const int h  = blockIdx.z;
  const int tid = threadIdx.x;
  const int w = tid >> 6, l = tid & 63;
  const int wm = w >> 2, wn = w & 3;
  __shared__ unsigned short As[128 * 64];
  __shared__ unsigned short Bs[256 * 64];
  const unsigned short* Ag = wt + (size_t)h * OPAD * KPAD;
  f32x4 acc[4][4] = {};
  for (int kt = 0; kt < KPAD / 64; ++kt) {
    const int k0 = kt * 64;
#pragma unroll
    for (int r = 0; r < 2; ++r) {
      const unsigned short* g = Ag + (size_t)(m0 + r * 64 + w * 8 + (l >> 3)) * KPAD + k0 + (l & 7) * 8;
      async_ld16(g, &As[(r * 64 + w * 8) * 64]);
    }
#pragma unroll
    for (int r = 0; r < 4; ++r) {
      const unsigned short* g = xb + (size_t)(n0 + r * 64 + w * 8 + (l >> 3)) * KPAD + k0 + (l & 7) * 8;
      async_ld16(g, &Bs[(r * 64 + w * 8) * 64]);
    }
    __syncthreads();
#pragma unroll
    for (int ks = 0; ks < 2; ++ks) {
      bf16x8 af[4], bfr[4];
#pragma unroll
      for (int mi = 0; mi < 4; ++mi)
        af[mi] = *reinterpret_cast<const bf16x8*>(
            &As[(wm * 64 + mi * 16 + (l & 15)) * 64 + ks * 32 + (l >> 4) * 8]);
#pragma unroll
      for (int ni = 0; ni < 4; ++ni)
        bfr[ni] = *reinterpret_cast<const bf16x8*>(
            &Bs[(wn * 64 + ni * 16 + (l & 15)) * 64 + ks * 32 + (l >> 4) * 8]);
#pragma unroll
      for (int mi = 0; mi < 4; ++mi)
#pragma unroll
        for (int ni = 0; ni < 4; ++ni)
          acc[mi][ni] = __builtin_amdgcn_mfma_f32_16x16x32_bf16(af[mi], bfr[ni], acc[mi][ni], 0, 0, 0);
    }
    __syncthreads();
  }
  unsigned short* Wh = wht + (size_t)h * OPAD * NN;
#pragma unroll
  for (int mi = 0; mi < 4; ++mi)
#pragma unroll
    for (int j = 0; j < 4; ++j) {
      int o = m0 + wm * 64 + mi * 16 + (l >> 4) * 4 + j;
#pragma unroll
      for (int ni = 0; ni < 4; ++ni) {
        int n = n0 + wn * 64 + ni * 16 + (l & 15);
        float val = (o == FD) ? 1.0f : acc[mi][ni][j];  // pad rows are exactly 0; row FD = ones
        Wh[(size_t)o * NN + n] = f2bf(val);
      }
    }
  // ---- a1/a2 partial projections (f32 acc, per-(n) atomics) ----
  const float* ap1 = a + h * 2 * FD;
  const float* ap2 = ap1 + FD;
  float av1[4][4], av2[4][4];
#pragma unroll
  for (int mi = 0; mi < 4; ++mi)
#pragma unroll
    for (int j = 0; j < 4; ++j) {
      int o = m0 + wm * 64 + mi * 16 + (l >> 4) * 4 + j;
      bool ok = (o < FD);
      av1[mi][j] = ok ? ap1[o] : 0.f;
      av2[mi][j] = ok ? ap2[o] : 0.f;
    }
#pragma unroll
  for (int ni = 0; ni < 4; ++ni) {
    float p1 = 0.f, p2 = 0.f;
#pragma unroll
    for (int mi = 0; mi < 4; ++mi)
#pragma unroll
      for (int j = 0; j < 4; ++j) {
        p1 += acc[mi][ni][j] * av1[mi][j];
        p2 += acc[mi][ni][j] * av2[mi][j];
      }
    int n = n0 + wn * 64 + ni * 16 + (l & 15);
    unsafeAtomicAdd(&a1acc[h * NN + n], p1);
    unsafeAtomicAdd(&a2acc[h * NN + n], p2);
  }
}

// ---------- E/F factors from accumulated a1/a2 ----------
__global__ __launch_bounds__(256) void k_exp(const float* __restrict__ a1acc,
                                             const float* __restrict__ a2acc,
                                             float* __restrict__ e1s, float* __restrict__ f1s,
                                             float* __restrict__ e2s, float* __restrict__ f2s) {
  int i = blockIdx.x * 256 + threadIdx.x;
  if (i >= NH * NN) return;
  float s1 = a1acc[i] * LOG2E, s2 = a2acc[i] * LOG2E;
  e1s[i] = exp2f(s1);
  f1s[i] = exp2f(0.2f * s1);
  e2s[i] = exp2f(s2);
  f2s[i] = exp2f(0.2f * s2);
}

// ---------- PV: U[h][i][n] += sum_{j in kseg} w_ij WhT[n][j] ; column FD gives Z_i ----------
// w_ij = max(E1_i*E2_j, F1_i*F2_j)  (== exp2(log2e*lrelu(a1_i+a2_j)), exp2 monotone)
// The r7 measured-optimum configuration (381-390us, VGPR 56, 0 bank conflicts):
// BM=64 x BN=384, 8 waves, stage -> genA -> sync -> MFMA -> sync, no setprio,
// e2/f2 loaded before staging so genA doesn't wait on the gload_lds drain.
__global__ __launch_bounds__(512, 4) void k_pv(const unsigned short* __restrict__ wht,
                                               const float* __restrict__ e1s,
                                               const float* __restrict__ f1s,
                                               const float* __restrict__ e2s,
                                               const float* __restrict__ f2s,
                                               const uint64_t* __restrict__ bm,
                                               float* __restrict__ U) {
  const int m0 = blockIdx.x * 64;           // node rows i
  const int n0 = blockIdx.y * 384;          // feature cols
  const int h    = blockIdx.z / KS;
  const int kseg = blockIdx.z % KS;
  const int tid = threadIdx.x;
  const int w = tid >> 6, l = tid & 63;
  const int wu = __builtin_amdgcn_readfirstlane(w);
  // XOR-swizzled [rows][64] tiles (16B-block index ^= row&7)
  __shared__ unsigned short As[64 * 64];    // 8KB
  __shared__ unsigned short Bs[384 * 64];   // 48KB
  const unsigned short* Bg = wht + (size_t)h * OPAD * NN;
  const uint64_t* bmw = bm + (size_t)(m0 + wu * 8) * 128;
  float E1v[8], F1v[8];
#pragma unroll
  for (int r = 0; r < 8; ++r) {
    E1v[r] = e1s[h * NN + m0 + wu * 8 + r];
    F1v[r] = f1s[h * NN + m0 + wu * 8 + r];
  }

  const int kt0 = kseg * (NN / 64 / KS);
  const int ktend = kt0 + NN / 64 / KS;

  f32x4 acc[4][3] = {};

  for (int kt = kt0; kt < ktend; ++kt) {
    const int k0 = kt * 64;
    // e2/f2 FIRST: genA's first use then waits only on these, not the staging drain
    const float e2v = e2s[h * NN + k0 + l];
    const float f2v = f2s[h * NN + k0 + l];
    // stage B (Wh^T panel) async: linear LDS dest, source k-block pre-swizzled
#pragma unroll
    for (int call = 0; call < 6; ++call) {
      int c = call * 512 + tid;             // 16B-chunk index in [0, 3072)
      int row = c >> 3;
      int kb  = c & 7;
      int kbs = kb ^ (row & 7);
      const unsigned short* g = Bg + (size_t)(n0 + row) * NN + k0 + kbs * 8;
      async_ld16(g, &Bs[(size_t)c * 8]);
    }
    // generate A tile: wave handles 8 rows, lane = k within tile
#pragma unroll
    for (int r = 0; r < 8; ++r) {
      uint64_t mrow = bmw[(size_t)r * 128 + kt];
      uint32_t mlo = __builtin_amdgcn_readfirstlane((uint32_t)mrow);
      uint32_t mhi = __builtin_amdgcn_readfirstlane((uint32_t)(mrow >> 32));
      float e = fmaxf(E1v[r] * e2v, F1v[r] * f2v);
      e = selbit(e, mlo, mhi);
      As[(wu * 8 + r) * 64 + (l ^ (r << 3))] = f2bf(e);
    }
    __syncthreads();

#pragma unroll
    for (int ks = 0; ks < 2; ++ks) {
      bf16x8 af[4], bfr[3];
#pragma unroll
      for (int mi = 0; mi < 4; ++mi) {
        int row = mi * 16 + (l & 15);
        af[mi] = *reinterpret_cast<const bf16x8*>(
            &As[row * 64 + (((ks * 4 + (l >> 4)) ^ (row & 7)) * 8)]);
      }
#pragma unroll
      for (int ni = 0; ni < 3; ++ni) {
        int row = w * 48 + ni * 16 + (l & 15);
        bfr[ni] = *reinterpret_cast<const bf16x8*>(
            &Bs[row * 64 + (((ks * 4 + (l >> 4)) ^ (row & 7)) * 8)]);
      }
#pragma unroll
      for (int mi = 0; mi < 4; ++mi)
#pragma unroll
        for (int ni = 0; ni < 3; ++ni)
          acc[mi][ni] = __builtin_amdgcn_mfma_f32_16x16x32_bf16(af[mi], bfr[ni], acc[mi][ni], 0, 0, 0);
    }
    __syncthreads();
  }

#pragma unroll
  for (int mi = 0; mi < 4; ++mi)
#pragma unroll
    for (int j = 0; j < 4; ++j) {
      int i = m0 + mi * 16 + (l >> 4) * 4 + j;
#pragma unroll
      for (int ni = 0; ni < 3; ++ni) {
        int n = n0 + w * 48 + ni * 16 + (l & 15);
        if (n <= FD) unsafeAtomicAdd(&U[((size_t)h * NN + i) * USTRIDE + n], acc[mi][ni][j]);
      }
    }
}

// ---------- y = elu(mean_h U[h][i][o] / U[h][i][FD]) , 2 outputs/thread ----------
__global__ __launch_bounds__(256) void k_final(const float* __restrict__ U,
                                               float* __restrict__ y) {
  int idx = blockIdx.x * 256 + threadIdx.x;      // pair index
  if (idx >= NN * (FD / 2)) return;
  int i = idx / (FD / 2), p = idx - i * (FD / 2);
  int o = p * 2;
  const size_t HS = (size_t)NN * USTRIDE;
  float s0 = 0.f, s1 = 0.f;
#pragma unroll
  for (int h = 0; h < NH; ++h) {
    size_t b = h * HS + (size_t)i * USTRIDE;
    float2 u = *reinterpret_cast<const float2*>(&U[b + o]);
    float zi = 1.0f / U[b + FD];
    s0 += u.x * zi;
    s1 += u.y * zi;
  }
  s0 *= (1.f / 3.f);
  s1 *= (1.f / 3.f);
  float2 out;
  out.x = s0 > 0.f ? s0 : (expf(s0) - 1.f);
  out.y = s1 > 0.f ? s1 : (expf(s1) - 1.f);
  *reinterpret_cast<float2*>(&y[(size_t)i * FD + o]) = out;
}

extern "C" void kernel_launch(void* const* d_in, const int* in_sizes, int n_in,
                              void* d_out, int out_size, void* d_ws, size_t ws_size,
                              hipStream_t stream) {
  const float* x   = (const float*)d_in[0];
  const int*   adj = (const int*)d_in[1];
  const float* W   = (const float*)d_in[2];
  const float* a   = (const float*)d_in[3];
  float* y = (float*)d_out;

  char* ws = (char*)d_ws;
  size_t off = 0;
  auto alloc = [&](size_t bytes) {
    void* p = ws + off;
    off = (off + bytes + 255) & ~(size_t)255;
    return p;
  };
  unsigned short* xb  = (unsigned short*)alloc((size_t)NN * KPAD * 2);
  unsigned short* wt  = (unsigned short*)alloc((size_t)NH * OPAD * KPAD * 2);
  unsigned short* wht = (unsigned short*)alloc((size_t)NH * OPAD * NN * 2);
  float* e1s = (float*)alloc((size_t)NH * NN * 4);
  float* f1s = (float*)alloc((size_t)NH * NN * 4);
  float* e2s = (float*)alloc((size_t)NH * NN * 4);
  float* f2s = (float*)alloc((size_t)NH * NN * 4);
  uint64_t* bm = (uint64_t*)alloc((size_t)NN * 128 * 8);
  float* U = (float*)alloc((size_t)NH * NN * USTRIDE * 4);
  float* a1acc = (float*)alloc((size_t)NH * NN * 4);
  float* a2acc = (float*)alloc((size_t)NH * NN * 4);
  (void)ws_size; (void)in_sizes; (void)n_in; (void)out_size;

  hipMemsetAsync(U, 0, (size_t)NH * NN * USTRIDE * 4, stream);
  hipMemsetAsync(a1acc, 0, (size_t)NH * NN * 4 * 2, stream);

  const int cast_total = NN * KPAD + NH * OPAD * KPAD;
  k_cast<<<(cast_total + 255) / 256, 256, 0, stream>>>(x, W, xb, wt);
  k_pack<<<NN * 128 / 4, 256, 0, stream>>>(adj, bm);
  k_gemm_wht<<<dim3(OPAD / 128, NN / 256, NH), 512, 0, stream>>>(wt, xb, a, wht, a1acc, a2acc);
  k_exp<<<(NH * NN + 255) / 256, 256, 0, stream>>>(a1acc, a2acc, e1s, f1s, e2s, f2s);
  k_pv<<<dim3(NN / 64, 2, NH * KS), 512, 0, stream>>>(wht, e1s, f1s, e2s, f2s, bm, U);
  k_final<<<(NN * (FD / 2) + 255) / 256, 256, 0, stream>>>(U, y);
}

// Round 15
// 547.492 us; speedup vs baseline: 2.5988x; 1.1611x over previous
//
#include <hip/hip_runtime.h>
#include <hip/hip_bf16.h>
#include <stdint.h>

#define NN 8192
#define FD 690
#define NH 3
#define KPAD 704   // F_IN padded to mult of 64
#define OPAD 768   // F_OUT padded to mult of 128 (row FD holds constant 1 -> Z column)
#define USTRIDE 704
#define KS 2       // K-split factor for k_pv
#define LOG2E 1.4426950408889634f

typedef __attribute__((ext_vector_type(8))) short bf16x8;
typedef __attribute__((ext_vector_type(4))) float f32x4;

typedef __attribute__((address_space(1))) const void gas_t;
typedef __attribute__((address_space(3))) void las_t;

__device__ __forceinline__ void async_ld16(const void* g, void* l) {
  __builtin_amdgcn_global_load_lds((gas_t*)g, (las_t*)l, 16, 0, 0);
}

__device__ __forceinline__ float bf2f(unsigned short u) {
  return __uint_as_float(((unsigned int)u) << 16);
}
__device__ __forceinline__ unsigned short f2bf(float f) {
  __hip_bfloat16 h = __float2bfloat16(f);
  return *reinterpret_cast<unsigned short*>(&h);
}
// r = bit[lane] of (hi:lo) ? e : 0 — mask forced scalar via readfirstlane upstream
__device__ __forceinline__ float selbit(float e, uint32_t lo, uint32_t hi) {
  uint64_t m = ((uint64_t)hi << 32) | lo;
  float r;
  asm("v_cndmask_b32 %0, 0, %1, %2" : "=v"(r) : "v"(e), "s"(m));
  return r;
}

// ---------- fused cast / pad (xb vectorized 4x, then wt scalar) ----------
__global__ __launch_bounds__(256) void k_cast(const float* __restrict__ x,
                                              const float* __restrict__ W,
                                              unsigned short* __restrict__ xb,
                                              unsigned short* __restrict__ wt) {
  int q = blockIdx.x * 256 + threadIdx.x;
  const int XQ = NN * KPAD / 4;
  if (q < XQ) {
    int idx = q * 4;
    int n = idx / KPAD, f = idx - n * KPAD;   // f mult of 4
    uint2 out;
    if (f + 3 < FD) {
      const float* xp = &x[(size_t)n * FD + f];
      float2 a = *reinterpret_cast<const float2*>(xp);
      float2 b = *reinterpret_cast<const float2*>(xp + 2);
      out.x = (uint32_t)f2bf(a.x) | ((uint32_t)f2bf(a.y) << 16);
      out.y = (uint32_t)f2bf(b.x) | ((uint32_t)f2bf(b.y) << 16);
    } else {
      unsigned short e[4];
#pragma unroll
      for (int t = 0; t < 4; ++t) {
        int ff = f + t;
        e[t] = (ff < FD) ? f2bf(x[(size_t)n * FD + ff]) : 0;
      }
      out.x = (uint32_t)e[0] | ((uint32_t)e[1] << 16);
      out.y = (uint32_t)e[2] | ((uint32_t)e[3] << 16);
    }
    *reinterpret_cast<uint2*>(&xb[idx]) = out;
    return;
  }
  int idx = q - XQ;
  if (idx >= NH * OPAD * KPAD) return;
  int h = idx / (OPAD * KPAD);
  int rem = idx - h * OPAD * KPAD;
  int o = rem / KPAD, f = rem - o * KPAD;
  float v = (o < FD && f < FD) ? W[((size_t)h * FD + f) * FD + o] : 0.f;
  wt[idx] = f2bf(v);
}

// ---------- adjacency -> bitmask, int4 loads + shfl nibble tree ----------
__global__ __launch_bounds__(256) void k_pack(const int4* __restrict__ adj4,
                                              uint64_t* __restrict__ bm) {
  int gw = (blockIdx.x * 256 + threadIdx.x) >> 6;   // wave id; NN*32 total
  int lane = threadIdx.x & 63;
  int i = gw >> 5, seg = gw & 31;                   // seg: 256 cols = 4 mask words
  int4 v = adj4[(size_t)i * (NN / 4) + seg * 64 + lane];
  uint32_t nib = (uint32_t)(v.x > 0) | ((uint32_t)(v.y > 0) << 1)
               | ((uint32_t)(v.z > 0) << 2) | ((uint32_t)(v.w > 0) << 3);
  nib |= __shfl_xor(nib, 1) << 4;     // 8 bits valid at lane%2==0
  nib |= __shfl_xor(nib, 2) << 8;     // 16 bits valid at lane%4==0
  nib |= __shfl_xor(nib, 4) << 16;    // 32 bits valid at lane%8==0
  uint32_t hi = __shfl_xor(nib, 8);   // other half's 32 bits
  if ((lane & 15) == 0)
    bm[(size_t)i * 128 + seg * 4 + (lane >> 4)] = (uint64_t)nib | ((uint64_t)hi << 32);
}

// ---------- WhT[h][o][n] = sum_f x[n][f] W[h][f][o]  (bf16 out; row FD = 1.0) ----------
// Epilogue additionally folds the a1/a2 score projections (f32, atomics).
__global__ __launch_bounds__(512) void k_gemm_wht(const unsigned short* __restrict__ wt,
                                                  const unsigned short* __restrict__ xb,
                                                  const float* __restrict__ a,
                                                  unsigned short* __restrict__ wht,
                                                  float* __restrict__ a1acc,
                                                  float* __restrict__ a2acc) {
  const int m0 = blockIdx.x * 128;   // o
  const int n0 = blockIdx.y * 256;   // node
  const int h  = blockIdx.z;
  const int tid = threadIdx.x;
  const int w = tid >> 6, l = tid & 63;
  const int wm = w >> 2, wn = w & 3;
  __shared__ unsigned short As[128 * 64];
  __shared__ unsigned short Bs[256 * 64];
  const unsigned short* Ag = wt + (size_t)h * OPAD * KPAD;
  f32x4 acc[4][4] = {};
  for (int kt = 0; kt < KPAD / 64; ++kt) {
    const int k0 = kt * 64;
#pragma unroll
    for (int r = 0; r < 2; ++r) {
      const unsigned short* g = Ag + (size_t)(m0 + r * 64 + w * 8 + (l >> 3)) * KPAD + k0 + (l & 7) * 8;
      async_ld16(g, &As[(r * 64 + w * 8) * 64]);
    }
#pragma unroll
    for (int r = 0; r < 4; ++r) {
      const unsigned short* g = xb + (size_t)(n0 + r * 64 + w * 8 + (l >> 3)) * KPAD + k0 + (l & 7) * 8;
      async_ld16(g, &Bs[(r * 64 + w * 8) * 64]);
    }
    __syncthreads();
#pragma unroll
    for (int ks = 0; ks < 2; ++ks) {
      bf16x8 af[4], bfr[4];
#pragma unroll
      for (int mi = 0; mi < 4; ++mi)
        af[mi] = *reinterpret_cast<const bf16x8*>(
            &As[(wm * 64 + mi * 16 + (l & 15)) * 64 + ks * 32 + (l >> 4) * 8]);
#pragma unroll
      for (int ni = 0; ni < 4; ++ni)
        bfr[ni] = *reinterpret_cast<const bf16x8*>(
            &Bs[(wn * 64 + ni * 16 + (l & 15)) * 64 + ks * 32 + (l >> 4) * 8]);
#pragma unroll
      for (int mi = 0; mi < 4; ++mi)
#pragma unroll
        for (int ni = 0; ni < 4; ++ni)
          acc[mi][ni] = __builtin_amdgcn_mfma_f32_16x16x32_bf16(af[mi], bfr[ni], acc[mi][ni], 0, 0, 0);
    }
    __syncthreads();
  }
  unsigned short* Wh = wht + (size_t)h * OPAD * NN;
#pragma unroll
  for (int mi = 0; mi < 4; ++mi)
#pragma unroll
    for (int j = 0; j < 4; ++j) {
      int o = m0 + wm * 64 + mi * 16 + (l >> 4) * 4 + j;
#pragma unroll
      for (int ni = 0; ni < 4; ++ni) {
        int n = n0 + wn * 64 + ni * 16 + (l & 15);
        float val = (o == FD) ? 1.0f : acc[mi][ni][j];  // pad rows are exactly 0; row FD = ones
        Wh[(size_t)o * NN + n] = f2bf(val);
      }
    }
  // ---- a1/a2 partial projections (f32 acc, per-(n) atomics) ----
  const float* ap1 = a + h * 2 * FD;
  const float* ap2 = ap1 + FD;
  float av1[4][4], av2[4][4];
#pragma unroll
  for (int mi = 0; mi < 4; ++mi)
#pragma unroll
    for (int j = 0; j < 4; ++j) {
      int o = m0 + wm * 64 + mi * 16 + (l >> 4) * 4 + j;
      bool ok = (o < FD);
      av1[mi][j] = ok ? ap1[o] : 0.f;
      av2[mi][j] = ok ? ap2[o] : 0.f;
    }
#pragma unroll
  for (int ni = 0; ni < 4; ++ni) {
    float p1 = 0.f, p2 = 0.f;
#pragma unroll
    for (int mi = 0; mi < 4; ++mi)
#pragma unroll
      for (int j = 0; j < 4; ++j) {
        p1 += acc[mi][ni][j] * av1[mi][j];
        p2 += acc[mi][ni][j] * av2[mi][j];
      }
    int n = n0 + wn * 64 + ni * 16 + (l & 15);
    unsafeAtomicAdd(&a1acc[h * NN + n], p1);
    unsafeAtomicAdd(&a2acc[h * NN + n], p2);
  }
}

// ---------- E/F factors from accumulated a1/a2 ----------
__global__ __launch_bounds__(256) void k_exp(const float* __restrict__ a1acc,
                                             const float* __restrict__ a2acc,
                                             float* __restrict__ e1s, float* __restrict__ f1s,
                                             float* __restrict__ e2s, float* __restrict__ f2s) {
  int i = blockIdx.x * 256 + threadIdx.x;
  if (i >= NH * NN) return;
  float s1 = a1acc[i] * LOG2E, s2 = a2acc[i] * LOG2E;
  e1s[i] = exp2f(s1);
  f1s[i] = exp2f(0.2f * s1);
  e2s[i] = exp2f(s2);
  f2s[i] = exp2f(0.2f * s2);
}

// ---------- PV: U{0,1}[h][i][n] (+)= sum_{j in kseg} w_ij WhT[n][j] ; column FD = Z ----------
// w_ij = max(E1_i*E2_j, F1_i*F2_j)  (== exp2(log2e*lrelu(a1_i+a2_j)), exp2 monotone)
// r7 measured-optimum loop (381-390us, VGPR 56, 0 bank conflicts), untouched.
// Epilogue: plain==1 -> kseg writes its own buffer (no RMW, no memset);
//           plain==0 -> atomicAdd into U0 (fallback when ws is small).
__global__ __launch_bounds__(512, 4) void k_pv(const unsigned short* __restrict__ wht,
                                               const float* __restrict__ e1s,
                                               const float* __restrict__ f1s,
                                               const float* __restrict__ e2s,
                                               const float* __restrict__ f2s,
                                               const uint64_t* __restrict__ bm,
                                               float* __restrict__ U0,
                                               float* __restrict__ U1,
                                               int plain) {
  const int m0 = blockIdx.x * 64;           // node rows i
  const int n0 = blockIdx.y * 384;          // feature cols
  const int h    = blockIdx.z / KS;
  const int kseg = blockIdx.z % KS;
  const int tid = threadIdx.x;
  const int w = tid >> 6, l = tid & 63;
  const int wu = __builtin_amdgcn_readfirstlane(w);
  // XOR-swizzled [rows][64] tiles (16B-block index ^= row&7)
  __shared__ unsigned short As[64 * 64];    // 8KB
  __shared__ unsigned short Bs[384 * 64];   // 48KB
  const unsigned short* Bg = wht + (size_t)h * OPAD * NN;
  const uint64_t* bmw = bm + (size_t)(m0 + wu * 8) * 128;
  float E1v[8], F1v[8];
#pragma unroll
  for (int r = 0; r < 8; ++r) {
    E1v[r] = e1s[h * NN + m0 + wu * 8 + r];
    F1v[r] = f1s[h * NN + m0 + wu * 8 + r];
  }

  const int kt0 = kseg * (NN / 64 / KS);
  const int ktend = kt0 + NN / 64 / KS;

  f32x4 acc[4][3] = {};

  for (int kt = kt0; kt < ktend; ++kt) {
    const int k0 = kt * 64;
    // e2/f2 FIRST: genA's first use then waits only on these, not the staging drain
    const float e2v = e2s[h * NN + k0 + l];
    const float f2v = f2s[h * NN + k0 + l];
    // stage B (Wh^T panel) async: linear LDS dest, source k-block pre-swizzled
#pragma unroll
    for (int call = 0; call < 6; ++call) {
      int c = call * 512 + tid;             // 16B-chunk index in [0, 3072)
      int row = c >> 3;
      int kb  = c & 7;
      int kbs = kb ^ (row & 7);
      const unsigned short* g = Bg + (size_t)(n0 + row) * NN + k0 + kbs * 8;
      async_ld16(g, &Bs[(size_t)c * 8]);
    }
    // generate A tile: wave handles 8 rows, lane = k within tile
#pragma unroll
    for (int r = 0; r < 8; ++r) {
      uint64_t mrow = bmw[(size_t)r * 128 + kt];
      uint32_t mlo = __builtin_amdgcn_readfirstlane((uint32_t)mrow);
      uint32_t mhi = __builtin_amdgcn_readfirstlane((uint32_t)(mrow >> 32));
      float e = fmaxf(E1v[r] * e2v, F1v[r] * f2v);
      e = selbit(e, mlo, mhi);
      As[(wu * 8 + r) * 64 + (l ^ (r << 3))] = f2bf(e);
    }
    __syncthreads();

#pragma unroll
    for (int ks = 0; ks < 2; ++ks) {
      bf16x8 af[4], bfr[3];
#pragma unroll
      for (int mi = 0; mi < 4; ++mi) {
        int row = mi * 16 + (l & 15);
        af[mi] = *reinterpret_cast<const bf16x8*>(
            &As[row * 64 + (((ks * 4 + (l >> 4)) ^ (row & 7)) * 8)]);
      }
#pragma unroll
      for (int ni = 0; ni < 3; ++ni) {
        int row = w * 48 + ni * 16 + (l & 15);
        bfr[ni] = *reinterpret_cast<const bf16x8*>(
            &Bs[row * 64 + (((ks * 4 + (l >> 4)) ^ (row & 7)) * 8)]);
      }
#pragma unroll
      for (int mi = 0; mi < 4; ++mi)
#pragma unroll
        for (int ni = 0; ni < 3; ++ni)
          acc[mi][ni] = __builtin_amdgcn_mfma_f32_16x16x32_bf16(af[mi], bfr[ni], acc[mi][ni], 0, 0, 0);
    }
    __syncthreads();
  }

  float* Ud = (kseg == 0) ? U0 : U1;
#pragma unroll
  for (int mi = 0; mi < 4; ++mi)
#pragma unroll
    for (int j = 0; j < 4; ++j) {
      int i = m0 + mi * 16 + (l >> 4) * 4 + j;
#pragma unroll
      for (int ni = 0; ni < 3; ++ni) {
        int n = n0 + w * 48 + ni * 16 + (l & 15);
        if (n <= FD) {
          size_t off = ((size_t)h * NN + i) * USTRIDE + n;
          if (plain) Ud[off] = acc[mi][ni][j];
          else       unsafeAtomicAdd(&U0[off], acc[mi][ni][j]);
        }
      }
    }
}

// ---------- y = elu(mean_h U[h][i][o] / U[h][i][FD]) , 2 outputs/thread ----------
__global__ __launch_bounds__(256) void k_final(const float* __restrict__ U0,
                                               const float* __restrict__ U1,
                                               float* __restrict__ y,
                                               int two) {
  int idx = blockIdx.x * 256 + threadIdx.x;      // pair index
  if (idx >= NN * (FD / 2)) return;
  int i = idx / (FD / 2), p = idx - i * (FD / 2);
  int o = p * 2;
  const size_t HS = (size_t)NN * USTRIDE;
  float s0 = 0.f, s1 = 0.f;
#pragma unroll
  for (int h = 0; h < NH; ++h) {
    size_t b = h * HS + (size_t)i * USTRIDE;
    float2 u = *reinterpret_cast<const float2*>(&U0[b + o]);
    float z = U0[b + FD];
    if (two) {
      float2 u2 = *reinterpret_cast<const float2*>(&U1[b + o]);
      u.x += u2.x; u.y += u2.y;
      z += U1[b + FD];
    }
    float zi = 1.0f / z;
    s0 += u.x * zi;
    s1 += u.y * zi;
  }
  s0 *= (1.f / 3.f);
  s1 *= (1.f / 3.f);
  float2 out;
  out.x = s0 > 0.f ? s0 : (expf(s0) - 1.f);
  out.y = s1 > 0.f ? s1 : (expf(s1) - 1.f);
  *reinterpret_cast<float2*>(&y[(size_t)i * FD + o]) = out;
}

extern "C" void kernel_launch(void* const* d_in, const int* in_sizes, int n_in,
                              void* d_out, int out_size, void* d_ws, size_t ws_size,
                              hipStream_t stream) {
  const float* x   = (const float*)d_in[0];
  const int*   adj = (const int*)d_in[1];
  const float* W   = (const float*)d_in[2];
  const float* a   = (const float*)d_in[3];
  float* y = (float*)d_out;

  char* ws = (char*)d_ws;
  size_t off = 0;
  auto alloc = [&](size_t bytes) {
    void* p = ws + off;
    off = (off + bytes + 255) & ~(size_t)255;
    return p;
  };
  unsigned short* xb  = (unsigned short*)alloc((size_t)NN * KPAD * 2);
  unsigned short* wt  = (unsigned short*)alloc((size_t)NH * OPAD * KPAD * 2);
  unsigned short* wht = (unsigned short*)alloc((size_t)NH * OPAD * NN * 2);
  float* e1s = (float*)alloc((size_t)NH * NN * 4);
  float* f1s = (float*)alloc((size_t)NH * NN * 4);
  float* e2s = (float*)alloc((size_t)NH * NN * 4);
  float* f2s = (float*)alloc((size_t)NH * NN * 4);
  uint64_t* bm = (uint64_t*)alloc((size_t)NN * 128 * 8);
  float* U0 = (float*)alloc((size_t)NH * NN * USTRIDE * 4);
  float* a1acc = (float*)alloc((size_t)NH * NN * 4);
  float* a2acc = (float*)alloc((size_t)NH * NN * 4);
  const size_t usize = (size_t)NH * NN * USTRIDE * 4;
  bool two = (ws_size >= off + usize + 256);
  float* U1 = two ? (float*)alloc(usize) : U0;
  (void)in_sizes; (void)n_in; (void)out_size;

  if (!two) hipMemsetAsync(U0, 0, usize, stream);
  hipMemsetAsync(a1acc, 0, (size_t)NH * NN * 4 * 2, stream);

  const int cast_total = NN * KPAD / 4 + NH * OPAD * KPAD;
  k_cast<<<(cast_total + 255) / 256, 256, 0, stream>>>(x, W, xb, wt);
  k_pack<<<NN * 32 * 64 / 256, 256, 0, stream>>>((const int4*)adj, bm);
  k_gemm_wht<<<dim3(OPAD / 128, NN / 256, NH), 512, 0, stream>>>(wt, xb, a, wht, a1acc, a2acc);
  k_exp<<<(NH * NN + 255) / 256, 256, 0, stream>>>(a1acc, a2acc, e1s, f1s, e2s, f2s);
  k_pv<<<dim3(NN / 64, 2, NH * KS), 512, 0, stream>>>(wht, e1s, f1s, e2s, f2s, bm,
                                                      U0, U1, two ? 1 : 0);
  k_final<<<(NN * (FD / 2) + 255) / 256, 256, 0, stream>>>(U0, U1, y, two ? 1 : 0);
}